// Round 1
// 874.117 us; speedup vs baseline: 3.4409x; 3.4409x over previous
//
#include <hip/hip_runtime.h>

#define Bd 32
#define Ld 64
#define Hd 512
#define Vd 32000

typedef __bf16 bf16_t;
typedef __bf16 bf16x8 __attribute__((ext_vector_type(8)));
typedef float  f32x4  __attribute__((ext_vector_type(4)));

// ---------------------------------------------------------------------------
// K_pre: A = embed[tok] @ Wih + bih + bhh  for enc (blocks 0..127) and
// dec (blocks 128..255). 16 rows (n = t*32+b) per block.
// ---------------------------------------------------------------------------
__global__ void k_pre(
    const int* __restrict__ src, const int* __restrict__ tgt,
    const float* __restrict__ enc_embed, const float* __restrict__ enc_wih,
    const float* __restrict__ enc_bih, const float* __restrict__ enc_bhh,
    const float* __restrict__ dec_embed, const float* __restrict__ dec_wih,
    const float* __restrict__ dec_bih, const float* __restrict__ dec_bhh,
    float* __restrict__ Aenc, float* __restrict__ Adec)
{
    const int tid = threadIdx.x;
    const int bid = blockIdx.x;
    __shared__ float sm[16 * Hd];
    __shared__ int tokl[16];

    const bool isDec = bid >= 128;
    const int rb = (isDec ? bid - 128 : bid) << 4;      // 16 rows per block
    const int*   toks = isDec ? tgt : src;
    const float* emb  = isDec ? dec_embed : enc_embed;
    const float* wih  = isDec ? dec_wih : enc_wih;
    const float* bi   = isDec ? dec_bih : enc_bih;
    const float* bh   = isDec ? dec_bhh : enc_bhh;
    float*       A    = isDec ? Adec : Aenc;
    if (tid < 16) {
        int r = rb + tid;                    // n = t*32 + b
        tokl[tid] = toks[(r & 31) * Ld + (r >> 5)];
    }
    __syncthreads();
    #pragma unroll
    for (int u = 0; u < 8; ++u) {            // stage 16 embedding rows
        int f = tid + (u << 8);              // float4 index [0,2048)
        int row = f >> 7, c4 = f & 127;
        ((float4*)sm)[f] = ((const float4*)(emb + (size_t)tokl[row] * Hd))[c4];
    }
    __syncthreads();
    const int j0 = tid, j1 = tid + 256;
    float acc0[16], acc1[16];
    #pragma unroll
    for (int r = 0; r < 16; ++r) { acc0[r] = 0.f; acc1[r] = 0.f; }
    #pragma unroll 4
    for (int k = 0; k < Hd; ++k) {
        float w0 = wih[(size_t)k * Hd + j0];
        float w1 = wih[(size_t)k * Hd + j1];
        #pragma unroll
        for (int r = 0; r < 16; ++r) {
            float x = sm[r * Hd + k];
            acc0[r] += x * w0;
            acc1[r] += x * w1;
        }
    }
    float bb0 = bi[j0] + bh[j0], bb1 = bi[j1] + bh[j1];
    #pragma unroll
    for (int r = 0; r < 16; ++r) {
        A[(size_t)(rb + r) * Hd + j0] = acc0[r] + bb0;
        A[(size_t)(rb + r) * Hd + j1] = acc1[r] + bb1;
    }
}

// ---------------------------------------------------------------------------
// K_rec: recurrence. 256 blocks x 256 threads, plain launch (1 block/CU on
// 256 CUs => all blocks resident; spin-sync is capacity-safe).
// Block b: chain c = b&31, piece p = b>>5 owns 64 columns of Whh in VGPRs.
//
// Sync redesign: the data is its own flag. Each h element is an aligned
// 8-byte word {hi32 = step tag, lo32 = f32 bits}. Producers do ONE relaxed
// agent-scope 8B store; consumers poll their own two words directly.
// Single-copy atomicity of the aligned 8B store delivers tag+value together,
// so NO counter, NO fences, NO acquire/release, NO separate h load.
// 2-slot ring (slot = t&1) is safe: a block writing tag t has read all of
// tag t-1, which required every block to have fully read tag t-2, so
// overwriting the t-2 slot cannot race a reader.
// Exchange buffers are memset to 0xFF before launch so stale tags from a
// previous bench replay can never match a fresh expected tag.
// ---------------------------------------------------------------------------
__global__ __launch_bounds__(256, 1) void k_rec(
    const float* __restrict__ enc_whh, const float* __restrict__ dec_whh,
    const float* __restrict__ Aenc, const float* __restrict__ Adec,
    unsigned long long* __restrict__ encX, unsigned long long* __restrict__ decX,
    bf16_t* __restrict__ dhsB)
{
    const int tid = threadIdx.x;
    const int bid = blockIdx.x;
    const int c = bid & 31, p = bid >> 5;
    const int lane = tid & 63, q = tid >> 6;
    const int jb = p << 6;
    const int j = jb + lane;
    __shared__ float hl[Hd];
    __shared__ float part[256];

    { // encoder
        float wE[128];
        #pragma unroll
        for (int i = 0; i < 128; ++i) wE[i] = enc_whh[(size_t)(q * 128 + i) * Hd + j];
        for (int t = 0; t < Ld; ++t) {
            // hoist A load above the poll so its latency hides under the wait
            float aval = (tid < 64) ? Aenc[(size_t)(t * Bd + c) * Hd + jb + tid] : 0.f;
            if (t == 0) {
                hl[tid] = 0.f; hl[tid + 256] = 0.f;
            } else {
                const unsigned long long* xs = encX + (size_t)(((t - 1) & 1) * Bd + c) * Hd;
                const unsigned want = (unsigned)(t - 1);
                unsigned long long v0 = __hip_atomic_load(xs + tid,       __ATOMIC_RELAXED, __HIP_MEMORY_SCOPE_AGENT);
                unsigned long long v1 = __hip_atomic_load(xs + tid + 256, __ATOMIC_RELAXED, __HIP_MEMORY_SCOPE_AGENT);
                while ((unsigned)(v0 >> 32) != want || (unsigned)(v1 >> 32) != want) {
                    __builtin_amdgcn_s_sleep(1);
                    if ((unsigned)(v0 >> 32) != want)
                        v0 = __hip_atomic_load(xs + tid,       __ATOMIC_RELAXED, __HIP_MEMORY_SCOPE_AGENT);
                    if ((unsigned)(v1 >> 32) != want)
                        v1 = __hip_atomic_load(xs + tid + 256, __ATOMIC_RELAXED, __HIP_MEMORY_SCOPE_AGENT);
                }
                union { unsigned u; float f; } c0, c1;
                c0.u = (unsigned)v0; c1.u = (unsigned)v1;
                hl[tid] = c0.f; hl[tid + 256] = c1.f;
            }
            __syncthreads();
            float acc = 0.f;
            #pragma unroll
            for (int i = 0; i < 128; ++i) acc += wE[i] * hl[q * 128 + i];
            part[tid] = acc;
            __syncthreads();
            if (tid < 64) {
                float s4 = part[tid] + part[tid + 64] + part[tid + 128] + part[tid + 192];
                float h = tanhf(aval + s4);
                union { float f; unsigned u; } cv; cv.f = h;
                unsigned long long pv = ((unsigned long long)(unsigned)t << 32) | cv.u;
                __hip_atomic_store(encX + (size_t)((t & 1) * Bd + c) * Hd + jb + tid, pv,
                                   __ATOMIC_RELAXED, __HIP_MEMORY_SCOPE_AGENT);
            }
            __syncthreads();   // protects part[] reuse next iteration
        }
    }
    { // decoder
        float wD[128];
        #pragma unroll
        for (int i = 0; i < 128; ++i) wD[i] = dec_whh[(size_t)(q * 128 + i) * Hd + j];
        for (int s = 0; s < Ld; ++s) {
            float aval = (tid < 64) ? Adec[(size_t)(s * Bd + c) * Hd + jb + tid] : 0.f;
            {
                const unsigned long long* xs = (s == 0)
                    ? (encX + (size_t)(((Ld - 1) & 1) * Bd + c) * Hd)  // encoder final (slot 1)
                    : (decX + (size_t)(((s - 1) & 1) * Bd + c) * Hd);
                const unsigned want = (s == 0) ? (unsigned)(Ld - 1) : (unsigned)(64 + s - 1);
                unsigned long long v0 = __hip_atomic_load(xs + tid,       __ATOMIC_RELAXED, __HIP_MEMORY_SCOPE_AGENT);
                unsigned long long v1 = __hip_atomic_load(xs + tid + 256, __ATOMIC_RELAXED, __HIP_MEMORY_SCOPE_AGENT);
                while ((unsigned)(v0 >> 32) != want || (unsigned)(v1 >> 32) != want) {
                    __builtin_amdgcn_s_sleep(1);
                    if ((unsigned)(v0 >> 32) != want)
                        v0 = __hip_atomic_load(xs + tid,       __ATOMIC_RELAXED, __HIP_MEMORY_SCOPE_AGENT);
                    if ((unsigned)(v1 >> 32) != want)
                        v1 = __hip_atomic_load(xs + tid + 256, __ATOMIC_RELAXED, __HIP_MEMORY_SCOPE_AGENT);
                }
                union { unsigned u; float f; } c0, c1;
                c0.u = (unsigned)v0; c1.u = (unsigned)v1;
                hl[tid] = c0.f; hl[tid + 256] = c1.f;
            }
            __syncthreads();
            float acc = 0.f;
            #pragma unroll
            for (int i = 0; i < 128; ++i) acc += wD[i] * hl[q * 128 + i];
            part[tid] = acc;
            __syncthreads();
            if (tid < 64) {
                float s4 = part[tid] + part[tid + 64] + part[tid + 128] + part[tid + 192];
                float h = tanhf(aval + s4);
                union { float f; unsigned u; } cv; cv.f = h;
                unsigned long long pv = ((unsigned long long)(unsigned)(64 + s) << 32) | cv.u;
                __hip_atomic_store(decX + (size_t)((s & 1) * Bd + c) * Hd + jb + tid, pv,
                                   __ATOMIC_RELAXED, __HIP_MEMORY_SCOPE_AGENT);
                dhsB[((size_t)c * Ld + s) * Hd + jb + tid] = (bf16_t)h;   // (b,t,k) for GEMM
            }
            __syncthreads();
        }
    }
}

// ---------------------------------------------------------------------------
// K2: h2o_w (512 x 32000 f32) -> wT (32000 x 512 bf16), transposed convert
// ---------------------------------------------------------------------------
__global__ void k_wcvt(const float* __restrict__ w, bf16_t* __restrict__ wT)
{
    __shared__ float ls[64][65];
    const int tid = threadIdx.x;
    const int v0 = blockIdx.x << 6;   // 500
    const int k0 = blockIdx.y << 6;   // 8
    #pragma unroll
    for (int u = 0; u < 16; ++u) {
        int f = tid + (u << 8);
        int r = f >> 6, cc = f & 63;
        ls[r][cc] = w[(size_t)(k0 + r) * Vd + v0 + cc];
    }
    __syncthreads();
    #pragma unroll
    for (int u = 0; u < 16; ++u) {
        int f = tid + (u << 8);
        int vr = f >> 6, kk = f & 63;
        wT[(size_t)(v0 + vr) * Hd + k0 + kk] = (bf16_t)ls[kk][vr];
    }
}

// ---------------------------------------------------------------------------
// K3: logits = dhsB (2048 x 512 bf16) @ wT^T + bias -> out (fp32, raw logits)
// 128x128 tile per block, 16x16x32 bf16 MFMA, XOR-swizzled LDS.
// ---------------------------------------------------------------------------
__global__ __launch_bounds__(256, 2) void k_gemm(
    const bf16_t* __restrict__ Amat, const bf16_t* __restrict__ Bmat,
    const float* __restrict__ bias, float* __restrict__ out)
{
    __shared__ bf16_t At[128 * 32];
    __shared__ bf16_t Bt[128 * 32];
    const int tid = threadIdx.x;
    const int n0 = blockIdx.x << 7;     // 16 tiles
    const int v0 = blockIdx.y << 7;     // 250 tiles
    const int w = tid >> 6, lane = tid & 63;
    const int l15 = lane & 15, q8 = lane >> 4;
    const int moff = (w & 1) << 6, voff = (w >> 1) << 6;

    f32x4 acc[4][4];
    #pragma unroll
    for (int mi = 0; mi < 4; ++mi)
        #pragma unroll
        for (int vi = 0; vi < 4; ++vi)
            acc[mi][vi] = f32x4{0.f, 0.f, 0.f, 0.f};

    for (int kb = 0; kb < 16; ++kb) {
        __syncthreads();
        #pragma unroll
        for (int u = 0; u < 2; ++u) {
            int f = tid + (u << 8);              // [0,512): 16B chunks
            int row = f >> 2, sub = f & 3;
            int subw = sub ^ (row & 3);          // bank swizzle
            uint4 av = *(const uint4*)(Amat + ((size_t)(n0 + row) * Hd + (kb << 5) + (sub << 3)));
            *(uint4*)(At + row * 32 + (subw << 3)) = av;
            uint4 bv = *(const uint4*)(Bmat + ((size_t)(v0 + row) * Hd + (kb << 5) + (sub << 3)));
            *(uint4*)(Bt + row * 32 + (subw << 3)) = bv;
        }
        __syncthreads();
        bf16x8 af[4], bfr[4];
        #pragma unroll
        for (int mi = 0; mi < 4; ++mi) {
            int m = moff + (mi << 4) + l15;
            af[mi] = *(const bf16x8*)(At + m * 32 + (((q8 ^ (m & 3)) & 3) << 3));
        }
        #pragma unroll
        for (int vi = 0; vi < 4; ++vi) {
            int vv = voff + (vi << 4) + l15;
            bfr[vi] = *(const bf16x8*)(Bt + vv * 32 + (((q8 ^ (vv & 3)) & 3) << 3));
        }
        #pragma unroll
        for (int mi = 0; mi < 4; ++mi)
            #pragma unroll
            for (int vi = 0; vi < 4; ++vi)
                acc[mi][vi] = __builtin_amdgcn_mfma_f32_16x16x32_bf16(af[mi], bfr[vi], acc[mi][vi], 0, 0, 0);
    }
    #pragma unroll
    for (int vi = 0; vi < 4; ++vi) {
        int col = v0 + voff + (vi << 4) + l15;
        float bz = bias[col];
        #pragma unroll
        for (int mi = 0; mi < 4; ++mi) {
            int row = n0 + moff + (mi << 4) + (q8 << 2);
            #pragma unroll
            for (int r = 0; r < 4; ++r)
                out[(size_t)(row + r) * Vd + col] = acc[mi][vi][r] + bz;
        }
    }
}

// ---------------------------------------------------------------------------
// K4: per-row logZ = max + log(sum(exp(x-max))), online, one block per row
// ---------------------------------------------------------------------------
__global__ void k_logz(const float* __restrict__ out, float* __restrict__ logZ)
{
    const int n = blockIdx.x, tid = threadIdx.x;
    const float* row = out + (size_t)n * Vd;
    float m = -3.4e38f, l = 0.f;
    for (int i = 0; i < 125; ++i) {
        float x = row[i * 256 + tid];
        float nm = fmaxf(m, x);
        l = l * __expf(m - nm) + __expf(x - nm);
        m = nm;
    }
    __shared__ float smx[256], sl[256];
    smx[tid] = m; sl[tid] = l;
    __syncthreads();
    for (int s2 = 128; s2 > 0; s2 >>= 1) {
        if (tid < s2) {
            float m1 = smx[tid], l1 = sl[tid];
            float m2 = smx[tid + s2], l2 = sl[tid + s2];
            float nm = fmaxf(m1, m2);
            sl[tid] = l1 * __expf(m1 - nm) + l2 * __expf(m2 - nm);
            smx[tid] = nm;
        }
        __syncthreads();
    }
    if (tid == 0) logZ[n] = smx[0] + __logf(sl[0]);
}

// ---------------------------------------------------------------------------
// K5: out -= logZ[row], in place, float4
// ---------------------------------------------------------------------------
__global__ void k_sub(float* __restrict__ out, const float* __restrict__ logZ)
{
    int i4 = blockIdx.x * 256 + threadIdx.x;
    int n = i4 / 8000;                 // 32000/4 float4 per row
    float z = logZ[n];
    float4 x = ((const float4*)out)[i4];
    x.x -= z; x.y -= z; x.z -= z; x.w -= z;
    ((float4*)out)[i4] = x;
}

// ---------------------------------------------------------------------------
extern "C" void kernel_launch(void* const* d_in, const int* in_sizes, int n_in,
                              void* d_out, int out_size, void* d_ws, size_t ws_size,
                              hipStream_t stream)
{
    const int*   src       = (const int*)d_in[0];
    const int*   tgt       = (const int*)d_in[1];
    const float* enc_embed = (const float*)d_in[2];
    const float* enc_wih   = (const float*)d_in[3];
    const float* enc_bih   = (const float*)d_in[4];
    const float* enc_whh   = (const float*)d_in[5];
    const float* enc_bhh   = (const float*)d_in[6];
    const float* dec_embed = (const float*)d_in[7];
    const float* dec_wih   = (const float*)d_in[8];
    const float* dec_bih   = (const float*)d_in[9];
    const float* dec_whh   = (const float*)d_in[10];
    const float* dec_bhh   = (const float*)d_in[11];
    const float* h2o_w     = (const float*)d_in[12];
    const float* h2o_b     = (const float*)d_in[13];
    float* out = (float*)d_out;

    char* ws = (char*)d_ws;
    float*  Aenc  = (float*)(ws);                        // 4 MB
    float*  Adec  = (float*)(ws + ((size_t)4 << 20));    // 4 MB
    unsigned long long* encX = (unsigned long long*)(ws + ((size_t)8 << 20));            // 256 KB (2-slot tagged ring)
    unsigned long long* decX = (unsigned long long*)(ws + ((size_t)8 << 20) + (256 << 10)); // 256 KB
    bf16_t* dhsB  = (bf16_t*)(ws + ((size_t)9 << 20));   // 2 MB
    bf16_t* wT    = (bf16_t*)(ws + ((size_t)12 << 20));  // 31.25 MB
    float*  logZ  = (float*)(ws + ((size_t)44 << 20));   // 8 KB

    // Invalidate stale tags from a previous replay (0xFFFFFFFF never matches).
    hipMemsetAsync(ws + ((size_t)8 << 20), 0xFF, (size_t)512 << 10, stream);

    k_wcvt<<<dim3(500, 8), 256, 0, stream>>>(h2o_w, wT);
    k_pre<<<256, 256, 0, stream>>>(src, tgt,
        enc_embed, enc_wih, enc_bih, enc_bhh,
        dec_embed, dec_wih, dec_bih, dec_bhh, Aenc, Adec);
    k_rec<<<256, 256, 0, stream>>>(enc_whh, dec_whh, Aenc, Adec,
        encX, decX, dhsB);
    k_gemm<<<dim3(16, 250), 256, 0, stream>>>(dhsB, wT, h2o_b, out);
    k_logz<<<dim3(2048), 256, 0, stream>>>(out, logZ);
    k_sub<<<64000, 256, 0, stream>>>(out, logZ);
}

// Round 2
// 858.417 us; speedup vs baseline: 3.5038x; 1.0183x over previous
//
#include <hip/hip_runtime.h>

#define Bd 32
#define Ld 64
#define Hd 512
#define Vd 32000

typedef __bf16 bf16_t;
typedef __bf16 bf16x8 __attribute__((ext_vector_type(8)));
typedef float  f32x4  __attribute__((ext_vector_type(4)));

// ---------------------------------------------------------------------------
// K_prep: fused prologue. Blocks 0..255: A = embed[tok] @ Wih + bih + bhh
// (enc blocks 0..127, dec 128..255) + clear exchange tags. Blocks 256..4255:
// transposed bf16 convert of h2o_w. Fusing lets the three independent
// prologue jobs overlap on the machine instead of serializing as 3 dispatches.
// ---------------------------------------------------------------------------
__global__ void k_prep(
    const int* __restrict__ src, const int* __restrict__ tgt,
    const float* __restrict__ enc_embed, const float* __restrict__ enc_wih,
    const float* __restrict__ enc_bih, const float* __restrict__ enc_bhh,
    const float* __restrict__ dec_embed, const float* __restrict__ dec_wih,
    const float* __restrict__ dec_bih, const float* __restrict__ dec_bhh,
    float* __restrict__ Aenc, float* __restrict__ Adec,
    const float* __restrict__ w, bf16_t* __restrict__ wT,
    unsigned long long* __restrict__ encX, unsigned long long* __restrict__ decX)
{
    __shared__ __align__(16) char smraw[33024];
    const int tid = threadIdx.x;
    const int bid = blockIdx.x;

    if (bid < 256) {
        // --- clear exchange tags (replaces hipMemsetAsync; 0xFF.. never matches a tag)
        {
            unsigned wgi = ((unsigned)bid << 8) + tid;       // 0..65535
            if (wgi < 32768) encX[wgi] = ~0ull;
            else             decX[wgi - 32768] = ~0ull;
        }
        float* sm  = (float*)smraw;                // 16*512 floats
        int*  tokl = (int*)(smraw + 32768);
        const bool isDec = bid >= 128;
        const int rb = (isDec ? bid - 128 : bid) << 4;      // 16 rows per block
        const int*   toks = isDec ? tgt : src;
        const float* emb  = isDec ? dec_embed : enc_embed;
        const float* wih  = isDec ? dec_wih : enc_wih;
        const float* bi   = isDec ? dec_bih : enc_bih;
        const float* bh   = isDec ? dec_bhh : enc_bhh;
        float*       A    = isDec ? Adec : Aenc;
        if (tid < 16) {
            int r = rb + tid;                    // n = t*32 + b
            tokl[tid] = toks[(r & 31) * Ld + (r >> 5)];
        }
        __syncthreads();
        #pragma unroll
        for (int u = 0; u < 8; ++u) {            // stage 16 embedding rows
            int f = tid + (u << 8);              // float4 index [0,2048)
            int row = f >> 7, c4 = f & 127;
            ((float4*)sm)[f] = ((const float4*)(emb + (size_t)tokl[row] * Hd))[c4];
        }
        __syncthreads();
        const int j0 = tid, j1 = tid + 256;
        float acc0[16], acc1[16];
        #pragma unroll
        for (int r = 0; r < 16; ++r) { acc0[r] = 0.f; acc1[r] = 0.f; }
        #pragma unroll 4
        for (int k = 0; k < Hd; ++k) {
            float w0 = wih[(size_t)k * Hd + j0];
            float w1 = wih[(size_t)k * Hd + j1];
            #pragma unroll
            for (int r = 0; r < 16; ++r) {
                float x = sm[r * Hd + k];
                acc0[r] += x * w0;
                acc1[r] += x * w1;
            }
        }
        float bb0 = bi[j0] + bh[j0], bb1 = bi[j1] + bh[j1];
        #pragma unroll
        for (int r = 0; r < 16; ++r) {
            A[(size_t)(rb + r) * Hd + j0] = acc0[r] + bb0;
            A[(size_t)(rb + r) * Hd + j1] = acc1[r] + bb1;
        }
    } else {
        // --- h2o_w (512 x 32000 f32) -> wT (32000 x 512 bf16)
        float (*ls)[65] = (float(*)[65])smraw;
        const int b2 = bid - 256;                 // 0..3999
        const int v0 = (b2 % 500) << 6;
        const int k0 = (b2 / 500) << 6;
        #pragma unroll
        for (int u = 0; u < 16; ++u) {
            int f = tid + (u << 8);
            int r = f >> 6, cc = f & 63;
            ls[r][cc] = w[(size_t)(k0 + r) * Vd + v0 + cc];
        }
        __syncthreads();
        #pragma unroll
        for (int u = 0; u < 16; ++u) {
            int f = tid + (u << 8);
            int vr = f >> 6, kk = f & 63;
            wT[(size_t)(v0 + vr) * Hd + k0 + kk] = (bf16_t)ls[kk][vr];
        }
    }
}

// ---------------------------------------------------------------------------
// K_rec: recurrence. 256 blocks x 256 threads (1 block/CU, all resident).
// Block b: chain c = b&31, piece p = b>>5 owns 64 columns of Whh.
//
// Sync: data-is-its-own-flag (tagged 8B words, relaxed agent atomics).
// This round: critical path cut from 4 barriers/step to 1:
//  - each wave owns 16 output cols; 512-sum split 4-ways WITHIN the wave,
//    combined by __shfl_xor(16|32) -> no part[] LDS reduce, no 2 barriers.
//  - hl double-buffered (parity of the consumed tag) -> no end-of-loop
//    barrier. The single mid barrier of step u+1 separates step-u readers
//    from step-u+2 writers of the same buffer.
// ---------------------------------------------------------------------------
__global__ __launch_bounds__(256, 1) void k_rec(
    const float* __restrict__ enc_whh, const float* __restrict__ dec_whh,
    const float* __restrict__ Aenc, const float* __restrict__ Adec,
    unsigned long long* __restrict__ encX, unsigned long long* __restrict__ decX,
    bf16_t* __restrict__ dhsB)
{
    const int tid = threadIdx.x;
    const int bid = blockIdx.x;
    const int c = bid & 31, p = bid >> 5;
    const int q = tid >> 6, lane = tid & 63;
    const int l4 = lane & 15, g = lane >> 4;
    const int jb = p << 6;
    const int col = jb + (q << 4) + l4;      // this thread's output column
    const int i0 = g << 7;                   // this thread's input chunk base
    __shared__ float hl[2][Hd];

    { // encoder
        float wE[128];
        #pragma unroll
        for (int i = 0; i < 128; ++i) wE[i] = enc_whh[(size_t)(i0 + i) * Hd + col];
        for (int t = 0; t < Ld; ++t) {
            const int par = (t + 1) & 1;
            float aval = (lane < 16) ? Aenc[(size_t)(t * Bd + c) * Hd + col] : 0.f;
            if (t == 0) {
                hl[par][tid] = 0.f; hl[par][tid + 256] = 0.f;
            } else {
                const unsigned long long* xs = encX + (size_t)(((t - 1) & 1) * Bd + c) * Hd;
                const unsigned want = (unsigned)(t - 1);
                unsigned long long v0 = __hip_atomic_load(xs + tid,       __ATOMIC_RELAXED, __HIP_MEMORY_SCOPE_AGENT);
                unsigned long long v1 = __hip_atomic_load(xs + tid + 256, __ATOMIC_RELAXED, __HIP_MEMORY_SCOPE_AGENT);
                while ((unsigned)(v0 >> 32) != want || (unsigned)(v1 >> 32) != want) {
                    __builtin_amdgcn_s_sleep(1);
                    if ((unsigned)(v0 >> 32) != want)
                        v0 = __hip_atomic_load(xs + tid,       __ATOMIC_RELAXED, __HIP_MEMORY_SCOPE_AGENT);
                    if ((unsigned)(v1 >> 32) != want)
                        v1 = __hip_atomic_load(xs + tid + 256, __ATOMIC_RELAXED, __HIP_MEMORY_SCOPE_AGENT);
                }
                union { unsigned u; float f; } c0, c1;
                c0.u = (unsigned)v0; c1.u = (unsigned)v1;
                hl[par][tid] = c0.f; hl[par][tid + 256] = c1.f;
            }
            __syncthreads();
            const float4* h4 = (const float4*)(&hl[par][i0]);
            float acc = 0.f;
            #pragma unroll
            for (int i = 0; i < 32; ++i) {
                float4 hv = h4[i];
                acc += wE[4*i]*hv.x + wE[4*i+1]*hv.y + wE[4*i+2]*hv.z + wE[4*i+3]*hv.w;
            }
            acc += __shfl_xor(acc, 16, 64);
            acc += __shfl_xor(acc, 32, 64);
            if (lane < 16) {
                float h = tanhf(aval + acc);
                union { float f; unsigned u; } cv; cv.f = h;
                unsigned long long pv = ((unsigned long long)(unsigned)t << 32) | cv.u;
                __hip_atomic_store(encX + (size_t)((t & 1) * Bd + c) * Hd + col, pv,
                                   __ATOMIC_RELAXED, __HIP_MEMORY_SCOPE_AGENT);
            }
        }
    }
    { // decoder
        float wD[128];
        #pragma unroll
        for (int i = 0; i < 128; ++i) wD[i] = dec_whh[(size_t)(i0 + i) * Hd + col];
        for (int s = 0; s < Ld; ++s) {
            const int par = (s + 1) & 1;
            float aval = (lane < 16) ? Adec[(size_t)(s * Bd + c) * Hd + col] : 0.f;
            {
                const unsigned long long* xs = (s == 0)
                    ? (encX + (size_t)(((Ld - 1) & 1) * Bd + c) * Hd)  // encoder final
                    : (decX + (size_t)(((s - 1) & 1) * Bd + c) * Hd);
                const unsigned want = (s == 0) ? (unsigned)(Ld - 1) : (unsigned)(64 + s - 1);
                unsigned long long v0 = __hip_atomic_load(xs + tid,       __ATOMIC_RELAXED, __HIP_MEMORY_SCOPE_AGENT);
                unsigned long long v1 = __hip_atomic_load(xs + tid + 256, __ATOMIC_RELAXED, __HIP_MEMORY_SCOPE_AGENT);
                while ((unsigned)(v0 >> 32) != want || (unsigned)(v1 >> 32) != want) {
                    __builtin_amdgcn_s_sleep(1);
                    if ((unsigned)(v0 >> 32) != want)
                        v0 = __hip_atomic_load(xs + tid,       __ATOMIC_RELAXED, __HIP_MEMORY_SCOPE_AGENT);
                    if ((unsigned)(v1 >> 32) != want)
                        v1 = __hip_atomic_load(xs + tid + 256, __ATOMIC_RELAXED, __HIP_MEMORY_SCOPE_AGENT);
                }
                union { unsigned u; float f; } c0, c1;
                c0.u = (unsigned)v0; c1.u = (unsigned)v1;
                hl[par][tid] = c0.f; hl[par][tid + 256] = c1.f;
            }
            __syncthreads();
            const float4* h4 = (const float4*)(&hl[par][i0]);
            float acc = 0.f;
            #pragma unroll
            for (int i = 0; i < 32; ++i) {
                float4 hv = h4[i];
                acc += wD[4*i]*hv.x + wD[4*i+1]*hv.y + wD[4*i+2]*hv.z + wD[4*i+3]*hv.w;
            }
            acc += __shfl_xor(acc, 16, 64);
            acc += __shfl_xor(acc, 32, 64);
            if (lane < 16) {
                float h = tanhf(aval + acc);
                union { float f; unsigned u; } cv; cv.f = h;
                unsigned long long pv = ((unsigned long long)(unsigned)(64 + s) << 32) | cv.u;
                __hip_atomic_store(decX + (size_t)((s & 1) * Bd + c) * Hd + col, pv,
                                   __ATOMIC_RELAXED, __HIP_MEMORY_SCOPE_AGENT);
                dhsB[((size_t)c * Ld + s) * Hd + col] = (bf16_t)h;   // (b,t,k) for GEMM
            }
        }
    }
}

// ---------------------------------------------------------------------------
// K3: logits = dhsB (2048 x 512 bf16) @ wT^T + bias -> out (fp32, raw logits)
// 128x128 tile, 16x16x32 bf16 MFMA, XOR-swizzled LDS.
// NEW: per-block softmax partials (per-row max & sumexp over its 128 cols)
// written to part2[vblk][n] so the separate full-read logZ pass disappears.
// ---------------------------------------------------------------------------
__global__ __launch_bounds__(256, 2) void k_gemm(
    const bf16_t* __restrict__ Amat, const bf16_t* __restrict__ Bmat,
    const float* __restrict__ bias, float* __restrict__ out,
    float2* __restrict__ part2)
{
    __shared__ bf16_t At[128 * 32];
    __shared__ bf16_t Bt[128 * 32];
    __shared__ float smM[128][2];
    __shared__ float smL[128][2];
    const int tid = threadIdx.x;
    const int n0 = blockIdx.x << 7;     // 16 tiles
    const int v0 = blockIdx.y << 7;     // 250 tiles
    const int w = tid >> 6, lane = tid & 63;
    const int l15 = lane & 15, q8 = lane >> 4;
    const int moff = (w & 1) << 6, voff = (w >> 1) << 6;

    f32x4 acc[4][4];
    #pragma unroll
    for (int mi = 0; mi < 4; ++mi)
        #pragma unroll
        for (int vi = 0; vi < 4; ++vi)
            acc[mi][vi] = f32x4{0.f, 0.f, 0.f, 0.f};

    for (int kb = 0; kb < 16; ++kb) {
        __syncthreads();
        #pragma unroll
        for (int u = 0; u < 2; ++u) {
            int f = tid + (u << 8);              // [0,512): 16B chunks
            int row = f >> 2, sub = f & 3;
            int subw = sub ^ (row & 3);          // bank swizzle
            uint4 av = *(const uint4*)(Amat + ((size_t)(n0 + row) * Hd + (kb << 5) + (sub << 3)));
            *(uint4*)(At + row * 32 + (subw << 3)) = av;
            uint4 bv = *(const uint4*)(Bmat + ((size_t)(v0 + row) * Hd + (kb << 5) + (sub << 3)));
            *(uint4*)(Bt + row * 32 + (subw << 3)) = bv;
        }
        __syncthreads();
        bf16x8 af[4], bfr[4];
        #pragma unroll
        for (int mi = 0; mi < 4; ++mi) {
            int m = moff + (mi << 4) + l15;
            af[mi] = *(const bf16x8*)(At + m * 32 + (((q8 ^ (m & 3)) & 3) << 3));
        }
        #pragma unroll
        for (int vi = 0; vi < 4; ++vi) {
            int vv = voff + (vi << 4) + l15;
            bfr[vi] = *(const bf16x8*)(Bt + vv * 32 + (((q8 ^ (vv & 3)) & 3) << 3));
        }
        #pragma unroll
        for (int mi = 0; mi < 4; ++mi)
            #pragma unroll
            for (int vi = 0; vi < 4; ++vi)
                acc[mi][vi] = __builtin_amdgcn_mfma_f32_16x16x32_bf16(af[mi], bfr[vi], acc[mi][vi], 0, 0, 0);
    }

    float bz[4];
    #pragma unroll
    for (int vi = 0; vi < 4; ++vi) bz[vi] = bias[v0 + voff + (vi << 4) + l15];

    // per-(mi,r) max over this lane's 4 cols, then across the 16-lane group
    float rm[16], rl[16];
    #pragma unroll
    for (int k = 0; k < 16; ++k) rm[k] = -3.4e38f;
    #pragma unroll
    for (int mi = 0; mi < 4; ++mi)
        #pragma unroll
        for (int r = 0; r < 4; ++r)
            #pragma unroll
            for (int vi = 0; vi < 4; ++vi)
                rm[mi * 4 + r] = fmaxf(rm[mi * 4 + r], acc[mi][vi][r] + bz[vi]);
    #pragma unroll
    for (int mask = 1; mask < 16; mask <<= 1)
        #pragma unroll
        for (int k = 0; k < 16; ++k)
            rm[k] = fmaxf(rm[k], __shfl_xor(rm[k], mask, 64));
    // sumexp with final max; fused with the logit store
    #pragma unroll
    for (int k = 0; k < 16; ++k) rl[k] = 0.f;
    #pragma unroll
    for (int vi = 0; vi < 4; ++vi) {
        int col = v0 + voff + (vi << 4) + l15;
        #pragma unroll
        for (int mi = 0; mi < 4; ++mi) {
            int row = n0 + moff + (mi << 4) + (q8 << 2);
            #pragma unroll
            for (int r = 0; r < 4; ++r) {
                float z = acc[mi][vi][r] + bz[vi];
                out[(size_t)(row + r) * Vd + col] = z;
                rl[mi * 4 + r] += __expf(z - rm[mi * 4 + r]);
            }
        }
    }
    #pragma unroll
    for (int mask = 1; mask < 16; mask <<= 1)
        #pragma unroll
        for (int k = 0; k < 16; ++k)
            rl[k] += __shfl_xor(rl[k], mask, 64);

    if (l15 == 0) {
        int half = w >> 1;
        #pragma unroll
        for (int mi = 0; mi < 4; ++mi)
            #pragma unroll
            for (int r = 0; r < 4; ++r) {
                int rloc = moff + (mi << 4) + (q8 << 2) + r;
                smM[rloc][half] = rm[mi * 4 + r];
                smL[rloc][half] = rl[mi * 4 + r];
            }
    }
    __syncthreads();
    if (tid < 128) {
        float m0 = smM[tid][0], m1 = smM[tid][1];
        float l0 = smL[tid][0], l1 = smL[tid][1];
        float M = fmaxf(m0, m1);
        float L = l0 * __expf(m0 - M) + l1 * __expf(m1 - M);
        part2[(size_t)blockIdx.y * 2048 + n0 + tid] = make_float2(M, L);
    }
}

// ---------------------------------------------------------------------------
// K4: fused logZ + subtract. One block per row: combine 250 partials ->
// logZ, then one read+write pass over the row. (Old k_logz full-row read
// pass is gone: -262 MB HBM.)
// ---------------------------------------------------------------------------
__global__ void k_lsub(float* __restrict__ out, const float2* __restrict__ part2)
{
    const int n = blockIdx.x, tid = threadIdx.x;
    __shared__ float smx[256], sl[256];
    float m = -3.4e38f, l = 0.f;
    if (tid < 250) {
        float2 pp = part2[(size_t)tid * 2048 + n];
        m = pp.x; l = pp.y;
    }
    smx[tid] = m; sl[tid] = l;
    __syncthreads();
    for (int s2 = 128; s2 > 0; s2 >>= 1) {
        if (tid < s2) {
            float m1 = smx[tid], l1 = sl[tid];
            float m2 = smx[tid + s2], l2 = sl[tid + s2];
            float nm = fmaxf(m1, m2);
            sl[tid] = l1 * __expf(m1 - nm) + l2 * __expf(m2 - nm);
            smx[tid] = nm;
        }
        __syncthreads();
    }
    const float z = smx[0] + __logf(sl[0]);
    float4* row = (float4*)(out + (size_t)n * Vd);
    #pragma unroll 4
    for (int i = 0; i < 31; ++i) {             // 31*256 = 7936 of 8000 float4
        int idx = i * 256 + tid;
        float4 x = row[idx];
        x.x -= z; x.y -= z; x.z -= z; x.w -= z;
        row[idx] = x;
    }
    if (tid < 64) {                            // tail 64 float4
        int idx = 7936 + tid;
        float4 x = row[idx];
        x.x -= z; x.y -= z; x.z -= z; x.w -= z;
        row[idx] = x;
    }
}

// ---------------------------------------------------------------------------
extern "C" void kernel_launch(void* const* d_in, const int* in_sizes, int n_in,
                              void* d_out, int out_size, void* d_ws, size_t ws_size,
                              hipStream_t stream)
{
    const int*   src       = (const int*)d_in[0];
    const int*   tgt       = (const int*)d_in[1];
    const float* enc_embed = (const float*)d_in[2];
    const float* enc_wih   = (const float*)d_in[3];
    const float* enc_bih   = (const float*)d_in[4];
    const float* enc_whh   = (const float*)d_in[5];
    const float* enc_bhh   = (const float*)d_in[6];
    const float* dec_embed = (const float*)d_in[7];
    const float* dec_wih   = (const float*)d_in[8];
    const float* dec_bih   = (const float*)d_in[9];
    const float* dec_whh   = (const float*)d_in[10];
    const float* dec_bhh   = (const float*)d_in[11];
    const float* h2o_w     = (const float*)d_in[12];
    const float* h2o_b     = (const float*)d_in[13];
    float* out = (float*)d_out;

    char* ws = (char*)d_ws;
    float*  Aenc  = (float*)(ws);                        // 4 MB (dead after k_rec)
    float*  Adec  = (float*)(ws + ((size_t)4 << 20));    // 4 MB
    unsigned long long* encX = (unsigned long long*)(ws + ((size_t)8 << 20));               // 256 KB
    unsigned long long* decX = (unsigned long long*)(ws + ((size_t)8 << 20) + (256 << 10)); // 256 KB
    bf16_t* dhsB  = (bf16_t*)(ws + ((size_t)9 << 20));   // 2 MB
    bf16_t* wT    = (bf16_t*)(ws + ((size_t)12 << 20));  // 31.25 MB
    float2* part2 = (float2*)(ws);                       // 4 MB, reuses Aenc (dead)

    k_prep<<<4256, 256, 0, stream>>>(src, tgt,
        enc_embed, enc_wih, enc_bih, enc_bhh,
        dec_embed, dec_wih, dec_bih, dec_bhh, Aenc, Adec,
        h2o_w, wT, encX, decX);
    k_rec<<<256, 256, 0, stream>>>(enc_whh, dec_whh, Aenc, Adec,
        encX, decX, dhsB);
    k_gemm<<<dim3(16, 250), 256, 0, stream>>>(dhsB, wT, h2o_b, out, part2);
    k_lsub<<<2048, 256, 0, stream>>>(out, part2);
}